// Round 7
// baseline (233.004 us; speedup 1.0000x reference)
//
#include <hip/hip_runtime.h>
#include <cstdint>
#include <cstddef>

typedef unsigned short u16;
typedef unsigned int   u32;
typedef __bf16 bf16x8 __attribute__((ext_vector_type(8)));
typedef float  f32x4  __attribute__((ext_vector_type(4)));
typedef float  f32x16 __attribute__((ext_vector_type(16)));
typedef u16    u16x8  __attribute__((ext_vector_type(8)));
typedef u16    u16x4  __attribute__((ext_vector_type(4)));
typedef u32    u32x2  __attribute__((ext_vector_type(2)));
typedef u32    u32x4  __attribute__((ext_vector_type(4)));

#define DI __device__ __forceinline__

constexpr int SEQ = 4096;
constexpr int DIM = 512;
constexpr int NH  = 8;
constexpr int HD  = 64;
// scale * log2(e): softmax in exp2 domain; folded into Q at GEMM-0 epilogue
constexpr float ATT_C1 = 0.125f * 1.44269504088896340736f;

DI u16 f2bf(float f) {   // round-half-up (<=1 ulp vs RNE)
  return (u16)((__builtin_bit_cast(u32, f) + 0x8000u) >> 16);
}

// pack two fp32 -> u32 of two bf16 (round-half-up): 2 adds + 1 v_perm
DI u32 pk2(float hi, float lo) {
  u32 uh = __builtin_bit_cast(u32, hi) + 0x8000u;
  u32 ul = __builtin_bit_cast(u32, lo) + 0x8000u;
  return __builtin_amdgcn_perm(uh, ul, 0x07060302u);
}

// ---------------------------------------------------------------------------
// Kernel 1: prep = wconv (blocks 0..511) + LayerNorm+cast (blocks 512..2559).
// ---------------------------------------------------------------------------
__global__ __launch_bounds__(256) void prep_kernel(
    const float* __restrict__ x, const float* __restrict__ gamma,
    const float* __restrict__ beta,
    const float* __restrict__ wq, const float* __restrict__ wk,
    const float* __restrict__ wv, const float* __restrict__ wfc,
    u16* __restrict__ Wb, u16* __restrict__ xn)
{
  if (blockIdx.x < 512) {
    const int idx  = blockIdx.x * 256 + threadIdx.x;
    const int base = idx * 8;
    const int mat  = base >> 18;
    const int off  = base & (512 * 512 - 1);
    const float* src = (mat == 0) ? wq : (mat == 1) ? wk : (mat == 2) ? wv : wfc;
    const float4 a = *(const float4*)(src + off);
    const float4 b = *(const float4*)(src + off + 4);
    u32x4 o = { pk2(a.y, a.x), pk2(a.w, a.z), pk2(b.y, b.x), pk2(b.w, b.z) };
    *(u32x4*)(Wb + base) = o;
    return;
  }
  const int row  = (blockIdx.x - 512) * 4 + (threadIdx.x >> 6);
  const int lane = threadIdx.x & 63;
  const float* xr = x + (size_t)row * DIM + lane * 8;
  const float4 a = *(const float4*)xr;
  const float4 b = *(const float4*)(xr + 4);
  float s = a.x + a.y + a.z + a.w + b.x + b.y + b.z + b.w;
  float q = a.x*a.x + a.y*a.y + a.z*a.z + a.w*a.w
          + b.x*b.x + b.y*b.y + b.z*b.z + b.w*b.w;
#pragma unroll
  for (int m = 1; m < 64; m <<= 1) {
    s += __shfl_xor(s, m, 64);
    q += __shfl_xor(q, m, 64);
  }
  const float mu = s * (1.0f / DIM);
  const float rs = rsqrtf(q * (1.0f / DIM) - mu * mu + 1e-5f);
  const float4 g0 = *(const float4*)(gamma + lane * 8);
  const float4 g1 = *(const float4*)(gamma + lane * 8 + 4);
  const float4 e0 = *(const float4*)(beta + lane * 8);
  const float4 e1 = *(const float4*)(beta + lane * 8 + 4);
  const float v0 = (a.x - mu) * rs * g0.x + e0.x;
  const float v1 = (a.y - mu) * rs * g0.y + e0.y;
  const float v2 = (a.z - mu) * rs * g0.z + e0.z;
  const float v3 = (a.w - mu) * rs * g0.w + e0.w;
  const float v4 = (b.x - mu) * rs * g1.x + e1.x;
  const float v5 = (b.y - mu) * rs * g1.y + e1.y;
  const float v6 = (b.z - mu) * rs * g1.z + e1.z;
  const float v7 = (b.w - mu) * rs * g1.w + e1.w;
  u32x4 o = { pk2(v1, v0), pk2(v3, v2), pk2(v5, v4), pk2(v7, v6) };
  *(u32x4*)(xn + (size_t)row * DIM + lane * 8) = o;
}

// ---------------------------------------------------------------------------
// Kernel 2: 128x128x(BK=64) bf16 MFMA GEMM, C = A @ W^T (W pre-bf16),
// register-prefetched staging.  N=1536 fused QKV; Q pre-scaled by ATT_C1.
// Epilogue routes C through LDS for coalesced 16B stores.
// ---------------------------------------------------------------------------
__global__ __launch_bounds__(256, 3) void gemm_qkv_kernel(
    const u16* __restrict__ A, const u16* __restrict__ Wb,
    u16* __restrict__ Qo, u16* __restrict__ Ko, u16* __restrict__ Vt)
{
  __shared__ u16 SH[2][128][72];
  const int m0 = blockIdx.y * 128, n0 = blockIdx.x * 128;
  const int t = threadIdx.x, wave = t >> 6, lane = t & 63;
  const int quad = lane >> 4, l15 = lane & 15;
  const int wm = wave >> 1, wn = wave & 1;
  const int mat = n0 >> 9;
  const u16* Wsrc = Wb + (size_t)mat * 512 * 512 + (size_t)(n0 & 511) * DIM;

  f32x4 acc[4][4];
#pragma unroll
  for (int i = 0; i < 4; i++)
#pragma unroll
    for (int j = 0; j < 4; j++)
#pragma unroll
      for (int r = 0; r < 4; r++) acc[i][j][r] = 0.0f;

  u16x8 pfA[4], pfB[4];
#pragma unroll
  for (int it = 0; it < 4; it++) {
    const int c4 = t + it * 256;
    const int r = c4 >> 3, off = (c4 & 7) * 8;
    pfA[it] = *(const u16x8*)(A + (size_t)(m0 + r) * DIM + off);
    pfB[it] = *(const u16x8*)(Wsrc + (size_t)r * DIM + off);
  }

  for (int kk = 0; kk < DIM; kk += 64) {
    __syncthreads();
#pragma unroll
    for (int it = 0; it < 4; it++) {
      const int c4 = t + it * 256;
      const int r = c4 >> 3, off = (c4 & 7) * 8;
      *(u16x8*)&SH[0][r][off] = pfA[it];
      *(u16x8*)&SH[1][r][off] = pfB[it];
    }
    if (kk + 64 < DIM) {
#pragma unroll
      for (int it = 0; it < 4; it++) {
        const int c4 = t + it * 256;
        const int r = c4 >> 3, off = (c4 & 7) * 8;
        pfA[it] = *(const u16x8*)(A + (size_t)(m0 + r) * DIM + kk + 64 + off);
        pfB[it] = *(const u16x8*)(Wsrc + (size_t)r * DIM + kk + 64 + off);
      }
    }
    __syncthreads();
#pragma unroll
    for (int kx = 0; kx < 2; kx++) {
      bf16x8 af[4], bfr[4];
#pragma unroll
      for (int i = 0; i < 4; i++)
        af[i] = *(const bf16x8*)&SH[0][wm * 64 + i * 16 + l15][kx * 32 + quad * 8];
#pragma unroll
      for (int j = 0; j < 4; j++)
        bfr[j] = *(const bf16x8*)&SH[1][wn * 64 + j * 16 + l15][kx * 32 + quad * 8];
#pragma unroll
      for (int i = 0; i < 4; i++)
#pragma unroll
        for (int j = 0; j < 4; j++)
          acc[i][j] = __builtin_amdgcn_mfma_f32_16x16x32_bf16(
              af[i], bfr[j], acc[i][j], 0, 0, 0);
    }
  }

  u16* SH2 = (u16*)SH;               // flat [128][144] view
  __syncthreads();
  if (mat < 2) {
    const float qs = (mat == 0) ? ATT_C1 : 1.0f;
#pragma unroll
    for (int i = 0; i < 4; i++) {
      const int mb = wm * 64 + i * 16 + quad * 4;
#pragma unroll
      for (int j = 0; j < 4; j++) {
        const int nn = wn * 64 + j * 16 + l15;
#pragma unroll
        for (int r = 0; r < 4; r++)
          SH2[(mb + r) * 144 + nn] = f2bf(acc[i][j][r] * qs);
      }
    }
    __syncthreads();
    const int mloc = t >> 1, nh = (t & 1) * 64;
    const int sg = m0 + mloc, b = sg >> 12, sl = sg & 4095;
    const int ng0 = (n0 & 511) + nh, h = ng0 >> 6;
    u16* dst = (mat == 0 ? Qo : Ko) +
               ((size_t)(b * NH + h) * SEQ + sl) * HD;
#pragma unroll
    for (int k = 0; k < 8; k++) {
      u16x8 vv = *(u16x8*)&SH2[mloc * 144 + nh + 8 * k];
      *(u16x8*)&dst[8 * k] = vv;
    }
  } else {
#pragma unroll
    for (int i = 0; i < 4; i++) {
      const int mb = wm * 64 + i * 16 + quad * 4;
#pragma unroll
      for (int j = 0; j < 4; j++) {
        const int nn = wn * 64 + j * 16 + l15;
        u32x2 w;
        w[0] = pk2(acc[i][j][1], acc[i][j][0]);
        w[1] = pk2(acc[i][j][3], acc[i][j][2]);
        *(u32x2*)&SH2[nn * 144 + mb] = w;
      }
    }
    __syncthreads();
    const int nloc = t >> 1, mh = (t & 1) * 64;
    const int ng = (n0 & 511) + nloc, h = ng >> 6, d = ng & 63;
    const int b = m0 >> 12, sb = (m0 & 4095) + mh;
    u16* dst = Vt + ((size_t)(b * NH + h) * HD + d) * SEQ + sb;
#pragma unroll
    for (int k = 0; k < 8; k++) {
      u16x8 vv = *(u16x8*)&SH2[nloc * 144 + mh + 8 * k];
      *(u16x8*)&dst[8 * k] = vv;
    }
  }
}

// ---------------------------------------------------------------------------
// Kernel 3: flash attention (non-causal, no-max softmax), R6 pipeline with
// the register budget pushed under the 128-reg unified-RF cliff:
//  - padded LDS restored (R4 layout: measured 0 bank conflicts; the R5/R6
//    XOR swizzle caused 4-way read conflicts = 8.4M cycles)
//  - Q fragments live in LDS (re-read per chunk; transient regs only)
//  - sacc shrunk 32->16 by processing the two 32-kr slabs sequentially
//  Target: oacc32 + sacc16 (acc) + pf32 + ~50 arch ~= 115 regs -> 4 w/SIMD;
//  LDS 45KB -> 3 blocks/CU -> 12 waves/CU (was 8 at 2 w/SIMD in R6).
// Register prefetch of chunk c+1 kept (R6: removed barrier vmcnt drain).
// ---------------------------------------------------------------------------
__global__ __launch_bounds__(256, 4) void attn_kernel(
    const u16* __restrict__ Q, const u16* __restrict__ K,
    const u16* __restrict__ Vt, u16* __restrict__ O)
{
  __shared__ u16 Kl[128][72];   // [kr][d]  padded: conflict-free (R4)
  __shared__ u16 Vl[64][136];   // [d][kr]  padded
  __shared__ u16 Ql[64][72];    // [q][d]   padded
  const int bid = blockIdx.x;
  const int qt = bid >> 4;
  const int bh = (bid & 7) * 2 + ((bid >> 3) & 1);   // XCD-locality swizzle
  const int b = bh >> 3, h = bh & 7;
  const int t = threadIdx.x, wave = t >> 6, lane = t & 63;
  const int l31 = lane & 31, hf = lane >> 5;
  const int qgrp = wave & 1, krh = wave >> 1;
  const u16* Qb = Q + ((size_t)bh * SEQ + qt * 64) * HD;
  const u16* Kb = K + (size_t)bh * SEQ * HD;
  const u16* Vb = Vt + (size_t)bh * HD * SEQ;

  // stage Q tile (64x64) once; first loop barrier makes it visible
#pragma unroll
  for (int it = 0; it < 2; it++) {
    const int s = t + it * 256;
    const int r = s >> 3, off = (s & 7) * 8;
    *(u16x8*)&Ql[r][off] = *(const u16x8*)(Qb + r * HD + off);
  }

  f32x16 oacc[2];
#pragma unroll
  for (int mt = 0; mt < 2; mt++)
#pragma unroll
    for (int r = 0; r < 16; r++) oacc[mt][r] = 0.0f;
  float lrun = 0.0f;

  // prefetch chunk 0 into registers
  u16x8 pfK[4], pfV[4];
#pragma unroll
  for (int it = 0; it < 4; it++) {
    const int c4 = t + it * 256;
    const int rK = c4 >> 3, offK = (c4 & 7) * 8;
    pfK[it] = *(const u16x8*)(Kb + (size_t)rK * HD + offK);
    const int dV = c4 >> 4, offV = (c4 & 15) * 8;
    pfV[it] = *(const u16x8*)(Vb + (size_t)dV * SEQ + offV);
  }

  for (int kc = 0; kc < SEQ; kc += 128) {
    __syncthreads();             // previous chunk's LDS reads complete
#pragma unroll
    for (int it = 0; it < 4; it++) {
      const int c4 = t + it * 256;
      const int rK = c4 >> 3, offK = (c4 & 7) * 8;
      *(u16x8*)&Kl[rK][offK] = pfK[it];
      const int dV = c4 >> 4, offV = (c4 & 15) * 8;
      *(u16x8*)&Vl[dV][offV] = pfV[it];
    }
    if (kc + 128 < SEQ) {        // issue next chunk's loads NOW
#pragma unroll
      for (int it = 0; it < 4; it++) {
        const int c4 = t + it * 256;
        const int rK = c4 >> 3, offK = (c4 & 7) * 8;
        pfK[it] = *(const u16x8*)(Kb + (size_t)(kc + 128 + rK) * HD + offK);
        const int dV = c4 >> 4, offV = (c4 & 15) * 8;
        pfV[it] = *(const u16x8*)(Vb + (size_t)dV * SEQ + kc + 128 + offV);
      }
    }
    __syncthreads();             // ds_writes visible (no vmcnt drain)

    // per 32-kr slab: QK -> exp2 -> PV  (sacc is a single f32x16)
#pragma unroll
    for (int mt = 0; mt < 2; mt++) {
      f32x16 sacc;
#pragma unroll
      for (int r = 0; r < 16; r++) sacc[r] = 0.0f;
      const int rowK = krh * 64 + mt * 32 + l31;
#pragma unroll
      for (int kk = 0; kk < 4; kk++) {
        const bf16x8 ka = *(const bf16x8*)&Kl[rowK][kk * 16 + hf * 8];
        const bf16x8 qa =
            *(const bf16x8*)&Ql[qgrp * 32 + l31][kk * 16 + hf * 8];
        sacc = __builtin_amdgcn_mfma_f32_32x32x16_bf16(ka, qa, sacc, 0, 0, 0);
      }
      float ps = 0.0f;
#pragma unroll
      for (int r = 0; r < 16; r++) {
        const float p = __builtin_amdgcn_exp2f(sacc[r]);
        sacc[r] = p;
        ps += p;
      }
      lrun += ps;
#pragma unroll
      for (int kx = 0; kx < 2; kx++) {
        const int g = kx * 8;
        const u32 a0 = pk2(sacc[g + 1], sacc[g + 0]);
        const u32 a1 = pk2(sacc[g + 3], sacc[g + 2]);
        const u32 b0 = pk2(sacc[g + 5], sacc[g + 4]);
        const u32 b1 = pk2(sacc[g + 7], sacc[g + 6]);
        const u32 s0 = hf ? a0 : b0;
        const u32 s1 = hf ? a1 : b1;
        const u32 r0 = __shfl_xor(s0, 32, 64);
        const u32 r1 = __shfl_xor(s1, 32, 64);
        u32x4 fr;
        fr[0] = hf ? r0 : a0;
        fr[1] = hf ? r1 : a1;
        fr[2] = hf ? b0 : r0;
        fr[3] = hf ? b1 : r1;
        const bf16x8 pb = __builtin_bit_cast(bf16x8, fr);
        const int kk2 = mt * 2 + kx;
#pragma unroll
        for (int mt2 = 0; mt2 < 2; mt2++) {
          const int rowV = mt2 * 32 + l31;
          const bf16x8 va =
              *(const bf16x8*)&Vl[rowV][krh * 64 + kk2 * 16 + hf * 8];
          oacc[mt2] = __builtin_amdgcn_mfma_f32_32x32x16_bf16(
              va, pb, oacc[mt2], 0, 0, 0);
        }
      }
    }
  }

  // cross-(kr-half) combine via LDS, then normalize + store
  float lt = lrun + __shfl_xor(lrun, 32, 64);
  __syncthreads();
  float* Ofs = (float*)&Kl[0][0];        // 2*32*68*4 + 256 = 17664 <= 18432
  float* Lfs = Ofs + 2 * 32 * 68;
  if (krh == 1) {
#pragma unroll
    for (int mt2 = 0; mt2 < 2; mt2++)
#pragma unroll
      for (int gg = 0; gg < 4; gg++) {
        f32x4 v = { oacc[mt2][4 * gg + 0], oacc[mt2][4 * gg + 1],
                    oacc[mt2][4 * gg + 2], oacc[mt2][4 * gg + 3] };
        *(f32x4*)&Ofs[(qgrp * 32 + l31) * 68 + 32 * mt2 + 8 * gg + 4 * hf] = v;
      }
    if (hf == 0) Lfs[qgrp * 32 + l31] = lt;
  }
  __syncthreads();
  if (krh == 0) {
    lt += Lfs[qgrp * 32 + l31];
    const float inv = 1.0f / lt;
    const int s = qt * 64 + qgrp * 32 + l31;
    u16* Ob = O + ((size_t)(b * SEQ + s)) * DIM + h * HD;
#pragma unroll
    for (int mt2 = 0; mt2 < 2; mt2++)
#pragma unroll
      for (int gg = 0; gg < 4; gg++) {
        const f32x4 v = *(const f32x4*)
            &Ofs[(qgrp * 32 + l31) * 68 + 32 * mt2 + 8 * gg + 4 * hf];
        u32x2 w;
        w[0] = pk2((oacc[mt2][4 * gg + 1] + v[1]) * inv,
                   (oacc[mt2][4 * gg + 0] + v[0]) * inv);
        w[1] = pk2((oacc[mt2][4 * gg + 3] + v[3]) * inv,
                   (oacc[mt2][4 * gg + 2] + v[2]) * inv);
        *(u32x2*)&Ob[32 * mt2 + 8 * gg + 4 * hf] = w;
      }
  }
}

// ---------------------------------------------------------------------------
// Kernel 4: output GEMM 64x64 tiles, register-prefetched staging.
// ---------------------------------------------------------------------------
__global__ __launch_bounds__(256, 3) void gemm_fc_kernel(
    const u16* __restrict__ A, const u16* __restrict__ Wb,
    float* __restrict__ Co)
{
  __shared__ u16 As[64][72];
  __shared__ u16 Bs[64][72];
  const int m0 = blockIdx.y * 64, n0 = blockIdx.x * 64;
  const int t = threadIdx.x, wave = t >> 6, lane = t & 63;
  const int quad = lane >> 4, l15 = lane & 15;
  const int wm = wave >> 1, wn = wave & 1;
  const u16* Wsrc = Wb + (size_t)3 * 512 * 512 + (size_t)n0 * DIM;

  f32x4 acc[2][2];
#pragma unroll
  for (int i = 0; i < 2; i++)
#pragma unroll
    for (int j = 0; j < 2; j++)
#pragma unroll
      for (int r = 0; r < 4; r++) acc[i][j][r] = 0.0f;

  u16x8 pfA[2], pfB[2];
#pragma unroll
  for (int it = 0; it < 2; it++) {
    const int c4 = t + it * 256;
    const int r = c4 >> 3, off = (c4 & 7) * 8;
    pfA[it] = *(const u16x8*)(A + (size_t)(m0 + r) * DIM + off);
    pfB[it] = *(const u16x8*)(Wsrc + (size_t)r * DIM + off);
  }

  for (int kk = 0; kk < DIM; kk += 64) {
    __syncthreads();
#pragma unroll
    for (int it = 0; it < 2; it++) {
      const int c4 = t + it * 256;
      const int r = c4 >> 3, off = (c4 & 7) * 8;
      *(u16x8*)&As[r][off] = pfA[it];
      *(u16x8*)&Bs[r][off] = pfB[it];
    }
    if (kk + 64 < DIM) {
#pragma unroll
      for (int it = 0; it < 2; it++) {
        const int c4 = t + it * 256;
        const int r = c4 >> 3, off = (c4 & 7) * 8;
        pfA[it] = *(const u16x8*)(A + (size_t)(m0 + r) * DIM + kk + 64 + off);
        pfB[it] = *(const u16x8*)(Wsrc + (size_t)r * DIM + kk + 64 + off);
      }
    }
    __syncthreads();
#pragma unroll
    for (int kx = 0; kx < 2; kx++) {
      bf16x8 af[2], bfr[2];
#pragma unroll
      for (int i = 0; i < 2; i++)
        af[i] = *(const bf16x8*)&As[wm * 32 + i * 16 + l15][kx * 32 + quad * 8];
#pragma unroll
      for (int j = 0; j < 2; j++)
        bfr[j] = *(const bf16x8*)&Bs[wn * 32 + j * 16 + l15][kx * 32 + quad * 8];
#pragma unroll
      for (int i = 0; i < 2; i++)
#pragma unroll
        for (int j = 0; j < 2; j++)
          acc[i][j] = __builtin_amdgcn_mfma_f32_16x16x32_bf16(
              af[i], bfr[j], acc[i][j], 0, 0, 0);
    }
  }

#pragma unroll
  for (int i = 0; i < 2; i++) {
    const int m = m0 + wm * 32 + i * 16 + quad * 4;
#pragma unroll
    for (int j = 0; j < 2; j++) {
      const int n = n0 + wn * 32 + j * 16 + l15;
#pragma unroll
      for (int r = 0; r < 4; r++)
        Co[(size_t)(m + r) * DIM + n] = acc[i][j][r];
    }
  }
}

// ---------------------------------------------------------------------------
extern "C" void kernel_launch(void* const* d_in, const int* in_sizes, int n_in,
                              void* d_out, int out_size, void* d_ws,
                              size_t ws_size, hipStream_t stream)
{
  const float* x     = (const float*)d_in[0];
  const float* gamma = (const float*)d_in[1];
  const float* beta  = (const float*)d_in[2];
  const float* wq    = (const float*)d_in[3];
  const float* wk    = (const float*)d_in[4];
  const float* wv    = (const float*)d_in[5];
  const float* wfc   = (const float*)d_in[6];
  float* out = (float*)d_out;

  char* ws = (char*)d_ws;
  u16* Qb = (u16*)(ws);                       //  8 MB [b,h,s,d] (pre-scaled)
  u16* Kb = (u16*)(ws + ((size_t)8  << 20));  //  8 MB [b,h,s,d]
  u16* Vt = (u16*)(ws + ((size_t)16 << 20));  //  8 MB [b,h,d,s]
  u16* Ob = (u16*)(ws + ((size_t)24 << 20));  //  8 MB [b,s,h*64+d]
  u16* Wb = (u16*)(ws + ((size_t)32 << 20));  //  2 MB bf16 weights
  u16* xn = (u16*)(ws + ((size_t)34 << 20));  //  8 MB [8192][512] bf16

  prep_kernel<<<2560, 256, 0, stream>>>(x, gamma, beta, wq, wk, wv, wfc,
                                        Wb, xn);
  gemm_qkv_kernel<<<dim3(12, 64), 256, 0, stream>>>(xn, Wb, Qb, Kb, Vt);
  attn_kernel<<<1024, 256, 0, stream>>>(Qb, Kb, Vt, Ob);
  gemm_fc_kernel<<<dim3(8, 128), 256, 0, stream>>>(Ob, Wb, out);
}

// Round 8
// 220.652 us; speedup vs baseline: 1.0560x; 1.0560x over previous
//
#include <hip/hip_runtime.h>
#include <cstdint>
#include <cstddef>

typedef unsigned short u16;
typedef unsigned int   u32;
typedef __bf16 bf16x8 __attribute__((ext_vector_type(8)));
typedef float  f32x4  __attribute__((ext_vector_type(4)));
typedef float  f32x16 __attribute__((ext_vector_type(16)));
typedef u16    u16x8  __attribute__((ext_vector_type(8)));
typedef u16    u16x4  __attribute__((ext_vector_type(4)));
typedef u32    u32x2  __attribute__((ext_vector_type(2)));
typedef u32    u32x4  __attribute__((ext_vector_type(4)));

#define DI __device__ __forceinline__

constexpr int SEQ = 4096;
constexpr int DIM = 512;
constexpr int NH  = 8;
constexpr int HD  = 64;
// scale * log2(e): softmax in exp2 domain; folded into Q at GEMM-0 epilogue
constexpr float ATT_C1 = 0.125f * 1.44269504088896340736f;

DI u16 f2bf(float f) {   // round-half-up (<=1 ulp vs RNE)
  return (u16)((__builtin_bit_cast(u32, f) + 0x8000u) >> 16);
}

// pack two fp32 -> u32 of two bf16 (round-half-up): 2 adds + 1 v_perm
DI u32 pk2(float hi, float lo) {
  u32 uh = __builtin_bit_cast(u32, hi) + 0x8000u;
  u32 ul = __builtin_bit_cast(u32, lo) + 0x8000u;
  return __builtin_amdgcn_perm(uh, ul, 0x07060302u);
}

// ---------------------------------------------------------------------------
// Kernel 1: prep = wconv (blocks 0..511) + LayerNorm+cast (blocks 512..2559).
// ---------------------------------------------------------------------------
__global__ __launch_bounds__(256) void prep_kernel(
    const float* __restrict__ x, const float* __restrict__ gamma,
    const float* __restrict__ beta,
    const float* __restrict__ wq, const float* __restrict__ wk,
    const float* __restrict__ wv, const float* __restrict__ wfc,
    u16* __restrict__ Wb, u16* __restrict__ xn)
{
  if (blockIdx.x < 512) {
    const int idx  = blockIdx.x * 256 + threadIdx.x;
    const int base = idx * 8;
    const int mat  = base >> 18;
    const int off  = base & (512 * 512 - 1);
    const float* src = (mat == 0) ? wq : (mat == 1) ? wk : (mat == 2) ? wv : wfc;
    const float4 a = *(const float4*)(src + off);
    const float4 b = *(const float4*)(src + off + 4);
    u32x4 o = { pk2(a.y, a.x), pk2(a.w, a.z), pk2(b.y, b.x), pk2(b.w, b.z) };
    *(u32x4*)(Wb + base) = o;
    return;
  }
  const int row  = (blockIdx.x - 512) * 4 + (threadIdx.x >> 6);
  const int lane = threadIdx.x & 63;
  const float* xr = x + (size_t)row * DIM + lane * 8;
  const float4 a = *(const float4*)xr;
  const float4 b = *(const float4*)(xr + 4);
  float s = a.x + a.y + a.z + a.w + b.x + b.y + b.z + b.w;
  float q = a.x*a.x + a.y*a.y + a.z*a.z + a.w*a.w
          + b.x*b.x + b.y*b.y + b.z*b.z + b.w*b.w;
#pragma unroll
  for (int m = 1; m < 64; m <<= 1) {
    s += __shfl_xor(s, m, 64);
    q += __shfl_xor(q, m, 64);
  }
  const float mu = s * (1.0f / DIM);
  const float rs = rsqrtf(q * (1.0f / DIM) - mu * mu + 1e-5f);
  const float4 g0 = *(const float4*)(gamma + lane * 8);
  const float4 g1 = *(const float4*)(gamma + lane * 8 + 4);
  const float4 e0 = *(const float4*)(beta + lane * 8);
  const float4 e1 = *(const float4*)(beta + lane * 8 + 4);
  const float v0 = (a.x - mu) * rs * g0.x + e0.x;
  const float v1 = (a.y - mu) * rs * g0.y + e0.y;
  const float v2 = (a.z - mu) * rs * g0.z + e0.z;
  const float v3 = (a.w - mu) * rs * g0.w + e0.w;
  const float v4 = (b.x - mu) * rs * g1.x + e1.x;
  const float v5 = (b.y - mu) * rs * g1.y + e1.y;
  const float v6 = (b.z - mu) * rs * g1.z + e1.z;
  const float v7 = (b.w - mu) * rs * g1.w + e1.w;
  u32x4 o = { pk2(v1, v0), pk2(v3, v2), pk2(v5, v4), pk2(v7, v6) };
  *(u32x4*)(xn + (size_t)row * DIM + lane * 8) = o;
}

// ---------------------------------------------------------------------------
// Kernel 2: 128x128x(BK=64) bf16 MFMA GEMM, C = A @ W^T (W pre-bf16),
// register-prefetched staging.  N=1536 fused QKV; Q pre-scaled by ATT_C1.
// Epilogue routes C through LDS for coalesced 16B stores.
// ---------------------------------------------------------------------------
__global__ __launch_bounds__(256, 3) void gemm_qkv_kernel(
    const u16* __restrict__ A, const u16* __restrict__ Wb,
    u16* __restrict__ Qo, u16* __restrict__ Ko, u16* __restrict__ Vt)
{
  __shared__ u16 SH[2][128][72];
  const int m0 = blockIdx.y * 128, n0 = blockIdx.x * 128;
  const int t = threadIdx.x, wave = t >> 6, lane = t & 63;
  const int quad = lane >> 4, l15 = lane & 15;
  const int wm = wave >> 1, wn = wave & 1;
  const int mat = n0 >> 9;
  const u16* Wsrc = Wb + (size_t)mat * 512 * 512 + (size_t)(n0 & 511) * DIM;

  f32x4 acc[4][4];
#pragma unroll
  for (int i = 0; i < 4; i++)
#pragma unroll
    for (int j = 0; j < 4; j++)
#pragma unroll
      for (int r = 0; r < 4; r++) acc[i][j][r] = 0.0f;

  u16x8 pfA[4], pfB[4];
#pragma unroll
  for (int it = 0; it < 4; it++) {
    const int c4 = t + it * 256;
    const int r = c4 >> 3, off = (c4 & 7) * 8;
    pfA[it] = *(const u16x8*)(A + (size_t)(m0 + r) * DIM + off);
    pfB[it] = *(const u16x8*)(Wsrc + (size_t)r * DIM + off);
  }

  for (int kk = 0; kk < DIM; kk += 64) {
    __syncthreads();
#pragma unroll
    for (int it = 0; it < 4; it++) {
      const int c4 = t + it * 256;
      const int r = c4 >> 3, off = (c4 & 7) * 8;
      *(u16x8*)&SH[0][r][off] = pfA[it];
      *(u16x8*)&SH[1][r][off] = pfB[it];
    }
    if (kk + 64 < DIM) {
#pragma unroll
      for (int it = 0; it < 4; it++) {
        const int c4 = t + it * 256;
        const int r = c4 >> 3, off = (c4 & 7) * 8;
        pfA[it] = *(const u16x8*)(A + (size_t)(m0 + r) * DIM + kk + 64 + off);
        pfB[it] = *(const u16x8*)(Wsrc + (size_t)r * DIM + kk + 64 + off);
      }
    }
    __syncthreads();
#pragma unroll
    for (int kx = 0; kx < 2; kx++) {
      bf16x8 af[4], bfr[4];
#pragma unroll
      for (int i = 0; i < 4; i++)
        af[i] = *(const bf16x8*)&SH[0][wm * 64 + i * 16 + l15][kx * 32 + quad * 8];
#pragma unroll
      for (int j = 0; j < 4; j++)
        bfr[j] = *(const bf16x8*)&SH[1][wn * 64 + j * 16 + l15][kx * 32 + quad * 8];
#pragma unroll
      for (int i = 0; i < 4; i++)
#pragma unroll
        for (int j = 0; j < 4; j++)
          acc[i][j] = __builtin_amdgcn_mfma_f32_16x16x32_bf16(
              af[i], bfr[j], acc[i][j], 0, 0, 0);
    }
  }

  u16* SH2 = (u16*)SH;               // flat [128][144] view
  __syncthreads();
  if (mat < 2) {
    const float qs = (mat == 0) ? ATT_C1 : 1.0f;
#pragma unroll
    for (int i = 0; i < 4; i++) {
      const int mb = wm * 64 + i * 16 + quad * 4;
#pragma unroll
      for (int j = 0; j < 4; j++) {
        const int nn = wn * 64 + j * 16 + l15;
#pragma unroll
        for (int r = 0; r < 4; r++)
          SH2[(mb + r) * 144 + nn] = f2bf(acc[i][j][r] * qs);
      }
    }
    __syncthreads();
    const int mloc = t >> 1, nh = (t & 1) * 64;
    const int sg = m0 + mloc, b = sg >> 12, sl = sg & 4095;
    const int ng0 = (n0 & 511) + nh, h = ng0 >> 6;
    u16* dst = (mat == 0 ? Qo : Ko) +
               ((size_t)(b * NH + h) * SEQ + sl) * HD;
#pragma unroll
    for (int k = 0; k < 8; k++) {
      u16x8 vv = *(u16x8*)&SH2[mloc * 144 + nh + 8 * k];
      *(u16x8*)&dst[8 * k] = vv;
    }
  } else {
#pragma unroll
    for (int i = 0; i < 4; i++) {
      const int mb = wm * 64 + i * 16 + quad * 4;
#pragma unroll
      for (int j = 0; j < 4; j++) {
        const int nn = wn * 64 + j * 16 + l15;
        u32x2 w;
        w[0] = pk2(acc[i][j][1], acc[i][j][0]);
        w[1] = pk2(acc[i][j][3], acc[i][j][2]);
        *(u32x2*)&SH2[nn * 144 + mb] = w;
      }
    }
    __syncthreads();
    const int nloc = t >> 1, mh = (t & 1) * 64;
    const int ng = (n0 & 511) + nloc, h = ng >> 6, d = ng & 63;
    const int b = m0 >> 12, sb = (m0 & 4095) + mh;
    u16* dst = Vt + ((size_t)(b * NH + h) * HD + d) * SEQ + sb;
#pragma unroll
    for (int k = 0; k < 8; k++) {
      u16x8 vv = *(u16x8*)&SH2[nloc * 144 + mh + 8 * k];
      *(u16x8*)&dst[8 * k] = vv;
    }
  }
}

// ---------------------------------------------------------------------------
// Kernel 3: flash attention (non-causal, no-max softmax), LDS-REUSE tiling.
// R4-R7 analysis: the LDS pipe was the top consumer (~65% busy; each 1KB
// fragment read fed exactly one MFMA).  New split: the 4 waves divide the
// 128-kr chunk (32 kr each) and ALL share the block's 64-q tile, with both
// q-groups' Q fragments in registers.  Each K-frag read now feeds 2 MFMAs
// (both q-tiles) and each V-frag read feeds 2 -> LDS reads per chunk-wave
// drop 16 -> 8.  Cost: oacc[2][2] = 64 acc regs (~180 total, 2 waves/SIMD
// -- fine: R5 vs R6 showed occupancy is not the binding resource).
// kr-partials combine once per block via a serialized 4-pass LDS reduction.
// Padded LDS (R4 layout, measured 0 conflicts); register prefetch of chunk
// c+1 (R6); no-max softmax w/ Q pre-scaled by scale*log2e (R3).
// P B-frags assembled in-register via cross-half shfl (verified R4-R6).
// ---------------------------------------------------------------------------
__global__ __launch_bounds__(256, 2) void attn_kernel(
    const u16* __restrict__ Q, const u16* __restrict__ K,
    const u16* __restrict__ Vt, u16* __restrict__ O)
{
  __shared__ u16 Kl[128][72];   // [kr][d]  padded, conflict-free
  __shared__ u16 Vl[64][136];   // [d][kr]  padded
  const int bid = blockIdx.x;
  const int qt = bid >> 4;
  const int bh = (bid & 7) * 2 + ((bid >> 3) & 1);   // XCD-locality swizzle
  const int b = bh >> 3, h = bh & 7;
  const int t = threadIdx.x, wave = t >> 6, lane = t & 63;
  const int l31 = lane & 31, hf = lane >> 5;
  const int kq = wave;                 // wave's 32-kr quarter of the chunk
  const u16* Qb = Q + ((size_t)bh * SEQ + qt * 64) * HD;
  const u16* Kb = K + (size_t)bh * SEQ * HD;
  const u16* Vb = Vt + (size_t)bh * HD * SEQ;

  // both q-groups' B-frags in registers (16 VGPRs), reused every chunk
  bf16x8 bq[2][4];
#pragma unroll
  for (int qg = 0; qg < 2; qg++)
#pragma unroll
    for (int kk = 0; kk < 4; kk++)
      bq[qg][kk] = *(const bf16x8*)
          (Qb + (size_t)(qg * 32 + l31) * HD + kk * 16 + hf * 8);

  f32x16 oacc[2][2];                   // [qg][d-half]
#pragma unroll
  for (int qg = 0; qg < 2; qg++)
#pragma unroll
    for (int mt = 0; mt < 2; mt++)
#pragma unroll
      for (int r = 0; r < 16; r++) oacc[qg][mt][r] = 0.0f;
  float lrun[2] = {0.0f, 0.0f};

  // prefetch chunk 0 into registers
  u16x8 pfK[4], pfV[4];
#pragma unroll
  for (int it = 0; it < 4; it++) {
    const int c4 = t + it * 256;
    const int rK = c4 >> 3, offK = (c4 & 7) * 8;
    pfK[it] = *(const u16x8*)(Kb + (size_t)rK * HD + offK);
    const int dV = c4 >> 4, offV = (c4 & 15) * 8;
    pfV[it] = *(const u16x8*)(Vb + (size_t)dV * SEQ + offV);
  }

  for (int kc = 0; kc < SEQ; kc += 128) {
    __syncthreads();             // previous chunk's LDS reads complete
#pragma unroll
    for (int it = 0; it < 4; it++) {
      const int c4 = t + it * 256;
      const int rK = c4 >> 3, offK = (c4 & 7) * 8;
      *(u16x8*)&Kl[rK][offK] = pfK[it];
      const int dV = c4 >> 4, offV = (c4 & 15) * 8;
      *(u16x8*)&Vl[dV][offV] = pfV[it];
    }
    if (kc + 128 < SEQ) {        // issue next chunk's loads NOW
#pragma unroll
      for (int it = 0; it < 4; it++) {
        const int c4 = t + it * 256;
        const int rK = c4 >> 3, offK = (c4 & 7) * 8;
        pfK[it] = *(const u16x8*)(Kb + (size_t)(kc + 128 + rK) * HD + offK);
        const int dV = c4 >> 4, offV = (c4 & 15) * 8;
        pfV[it] = *(const u16x8*)(Vb + (size_t)dV * SEQ + kc + 128 + offV);
      }
    }
    __syncthreads();             // ds_writes visible (no vmcnt drain)

    // S^T = K @ Q^T: wave's 32 kr x 64 q; each ka feeds BOTH q-tiles
    f32x16 sacc[2];
#pragma unroll
    for (int qg = 0; qg < 2; qg++)
#pragma unroll
      for (int r = 0; r < 16; r++) sacc[qg][r] = 0.0f;
#pragma unroll
    for (int kk = 0; kk < 4; kk++) {
      const int rowK = kq * 32 + l31;
      const bf16x8 ka = *(const bf16x8*)&Kl[rowK][kk * 16 + hf * 8];
#pragma unroll
      for (int qg = 0; qg < 2; qg++)
        sacc[qg] = __builtin_amdgcn_mfma_f32_32x32x16_bf16(
            ka, bq[qg][kk], sacc[qg], 0, 0, 0);
    }

    // p = 2^s (no max; Q pre-scaled), per-lane partial sums
#pragma unroll
    for (int qg = 0; qg < 2; qg++) {
      float ps = 0.0f;
#pragma unroll
      for (int r = 0; r < 16; r++) {
        const float p = __builtin_amdgcn_exp2f(sacc[qg][r]);
        sacc[qg][r] = p;
        ps += p;
      }
      lrun[qg] += ps;
    }

    // O^T += V^T @ P^T over wave's 32 kr; each va feeds BOTH q-tiles
    bf16x8 va[2][2];
#pragma unroll
    for (int kg = 0; kg < 2; kg++)
#pragma unroll
      for (int mt = 0; mt < 2; mt++)
        va[kg][mt] = *(const bf16x8*)
            &Vl[mt * 32 + l31][kq * 32 + kg * 16 + hf * 8];
#pragma unroll
    for (int qg = 0; qg < 2; qg++) {
#pragma unroll
      for (int kg = 0; kg < 2; kg++) {
        const int g = kg * 8;
        const u32 a0 = pk2(sacc[qg][g + 1], sacc[qg][g + 0]);
        const u32 a1 = pk2(sacc[qg][g + 3], sacc[qg][g + 2]);
        const u32 b0 = pk2(sacc[qg][g + 5], sacc[qg][g + 4]);
        const u32 b1 = pk2(sacc[qg][g + 7], sacc[qg][g + 6]);
        const u32 s0 = hf ? a0 : b0;
        const u32 s1 = hf ? a1 : b1;
        const u32 r0 = __shfl_xor(s0, 32, 64);
        const u32 r1 = __shfl_xor(s1, 32, 64);
        u32x4 fr;
        fr[0] = hf ? r0 : a0;
        fr[1] = hf ? r1 : a1;
        fr[2] = hf ? b0 : r0;
        fr[3] = hf ? b1 : r1;
        const bf16x8 pb = __builtin_bit_cast(bf16x8, fr);
#pragma unroll
        for (int mt = 0; mt < 2; mt++)
          oacc[qg][mt] = __builtin_amdgcn_mfma_f32_32x32x16_bf16(
              va[kg][mt], pb, oacc[qg][mt], 0, 0, 0);
      }
    }
  }

  // cross-wave (kr-quarter) combine: serialized 4-pass LDS reduction
  float lt[2];
#pragma unroll
  for (int qg = 0; qg < 2; qg++)
    lt[qg] = lrun[qg] + __shfl_xor(lrun[qg], 32, 64);
  __syncthreads();
  float* Obuf = (float*)&Kl[0][0];     // 64 x 68 fp32 = 17408 B (fits Kl)
  float* Lbuf = (float*)&Vl[0][0];     // 64 fp32 (Vl region is free now)
#pragma unroll 1
  for (int w = 0; w < 4; w++) {
    if (wave == w) {
#pragma unroll
      for (int qg = 0; qg < 2; qg++) {
#pragma unroll
        for (int mt = 0; mt < 2; mt++)
#pragma unroll
          for (int gg = 0; gg < 4; gg++) {
            float* p = &Obuf[(qg * 32 + l31) * 68 + mt * 32 + 8 * gg + 4 * hf];
            f32x4 v = { oacc[qg][mt][4 * gg + 0], oacc[qg][mt][4 * gg + 1],
                        oacc[qg][mt][4 * gg + 2], oacc[qg][mt][4 * gg + 3] };
            if (w != 0) {
              const f32x4 old = *(const f32x4*)p;
              v[0] += old[0]; v[1] += old[1]; v[2] += old[2]; v[3] += old[3];
            }
            *(f32x4*)p = v;
          }
        if (hf == 0) {
          float* lp = &Lbuf[qg * 32 + l31];
          *lp = (w == 0) ? lt[qg] : (*lp + lt[qg]);
        }
      }
    }
    __syncthreads();
  }

  // normalize + coalesced bf16 store: O[b][s][h*64+d]
#pragma unroll
  for (int it = 0; it < 2; it++) {
    const int seg = t + it * 256;
    const int q = seg >> 3, d0 = (seg & 7) * 8;
    const float inv = 1.0f / Lbuf[q];
    const f32x4 v0 = *(const f32x4*)&Obuf[q * 68 + d0];
    const f32x4 v1 = *(const f32x4*)&Obuf[q * 68 + d0 + 4];
    u32x2 w0;
    w0[0] = pk2(v0[1] * inv, v0[0] * inv);
    w0[1] = pk2(v0[3] * inv, v0[2] * inv);
    u32x2 w1;
    w1[0] = pk2(v1[1] * inv, v1[0] * inv);
    w1[1] = pk2(v1[3] * inv, v1[2] * inv);
    u16* Ob = O + ((size_t)(b * SEQ + qt * 64 + q)) * DIM + h * HD + d0;
    u32x4 wv = { w0[0], w0[1], w1[0], w1[1] };
    *(u32x4*)Ob = wv;
  }
}

// ---------------------------------------------------------------------------
// Kernel 4: output GEMM 64x64 tiles, register-prefetched staging.
// ---------------------------------------------------------------------------
__global__ __launch_bounds__(256, 3) void gemm_fc_kernel(
    const u16* __restrict__ A, const u16* __restrict__ Wb,
    float* __restrict__ Co)
{
  __shared__ u16 As[64][72];
  __shared__ u16 Bs[64][72];
  const int m0 = blockIdx.y * 64, n0 = blockIdx.x * 64;
  const int t = threadIdx.x, wave = t >> 6, lane = t & 63;
  const int quad = lane >> 4, l15 = lane & 15;
  const int wm = wave >> 1, wn = wave & 1;
  const u16* Wsrc = Wb + (size_t)3 * 512 * 512 + (size_t)n0 * DIM;

  f32x4 acc[2][2];
#pragma unroll
  for (int i = 0; i < 2; i++)
#pragma unroll
    for (int j = 0; j < 2; j++)
#pragma unroll
      for (int r = 0; r < 4; r++) acc[i][j][r] = 0.0f;

  u16x8 pfA[2], pfB[2];
#pragma unroll
  for (int it = 0; it < 2; it++) {
    const int c4 = t + it * 256;
    const int r = c4 >> 3, off = (c4 & 7) * 8;
    pfA[it] = *(const u16x8*)(A + (size_t)(m0 + r) * DIM + off);
    pfB[it] = *(const u16x8*)(Wsrc + (size_t)r * DIM + off);
  }

  for (int kk = 0; kk < DIM; kk += 64) {
    __syncthreads();
#pragma unroll
    for (int it = 0; it < 2; it++) {
      const int c4 = t + it * 256;
      const int r = c4 >> 3, off = (c4 & 7) * 8;
      *(u16x8*)&As[r][off] = pfA[it];
      *(u16x8*)&Bs[r][off] = pfB[it];
    }
    if (kk + 64 < DIM) {
#pragma unroll
      for (int it = 0; it < 2; it++) {
        const int c4 = t + it * 256;
        const int r = c4 >> 3, off = (c4 & 7) * 8;
        pfA[it] = *(const u16x8*)(A + (size_t)(m0 + r) * DIM + kk + 64 + off);
        pfB[it] = *(const u16x8*)(Wsrc + (size_t)r * DIM + kk + 64 + off);
      }
    }
    __syncthreads();
#pragma unroll
    for (int kx = 0; kx < 2; kx++) {
      bf16x8 af[2], bfr[2];
#pragma unroll
      for (int i = 0; i < 2; i++)
        af[i] = *(const bf16x8*)&As[wm * 32 + i * 16 + l15][kx * 32 + quad * 8];
#pragma unroll
      for (int j = 0; j < 2; j++)
        bfr[j] = *(const bf16x8*)&Bs[wn * 32 + j * 16 + l15][kx * 32 + quad * 8];
#pragma unroll
      for (int i = 0; i < 2; i++)
#pragma unroll
        for (int j = 0; j < 2; j++)
          acc[i][j] = __builtin_amdgcn_mfma_f32_16x16x32_bf16(
              af[i], bfr[j], acc[i][j], 0, 0, 0);
    }
  }

#pragma unroll
  for (int i = 0; i < 2; i++) {
    const int m = m0 + wm * 32 + i * 16 + quad * 4;
#pragma unroll
    for (int j = 0; j < 2; j++) {
      const int n = n0 + wn * 32 + j * 16 + l15;
#pragma unroll
      for (int r = 0; r < 4; r++)
        Co[(size_t)(m + r) * DIM + n] = acc[i][j][r];
    }
  }
}

// ---------------------------------------------------------------------------
extern "C" void kernel_launch(void* const* d_in, const int* in_sizes, int n_in,
                              void* d_out, int out_size, void* d_ws,
                              size_t ws_size, hipStream_t stream)
{
  const float* x     = (const float*)d_in[0];
  const float* gamma = (const float*)d_in[1];
  const float* beta  = (const float*)d_in[2];
  const float* wq    = (const float*)d_in[3];
  const float* wk    = (const float*)d_in[4];
  const float* wv    = (const float*)d_in[5];
  const float* wfc   = (const float*)d_in[6];
  float* out = (float*)d_out;

  char* ws = (char*)d_ws;
  u16* Qb = (u16*)(ws);                       //  8 MB [b,h,s,d] (pre-scaled)
  u16* Kb = (u16*)(ws + ((size_t)8  << 20));  //  8 MB [b,h,s,d]
  u16* Vt = (u16*)(ws + ((size_t)16 << 20));  //  8 MB [b,h,d,s]
  u16* Ob = (u16*)(ws + ((size_t)24 << 20));  //  8 MB [b,s,h*64+d]
  u16* Wb = (u16*)(ws + ((size_t)32 << 20));  //  2 MB bf16 weights
  u16* xn = (u16*)(ws + ((size_t)34 << 20));  //  8 MB [8192][512] bf16

  prep_kernel<<<2560, 256, 0, stream>>>(x, gamma, beta, wq, wk, wv, wfc,
                                        Wb, xn);
  gemm_qkv_kernel<<<dim3(12, 64), 256, 0, stream>>>(xn, Wb, Qb, Kb, Vt);
  attn_kernel<<<1024, 256, 0, stream>>>(Qb, Kb, Vt, Ob);
  gemm_fc_kernel<<<dim3(8, 128), 256, 0, stream>>>(Ob, Wb, out);
}